// Round 4
// baseline (810.898 us; speedup 1.0000x reference)
//
#include <hip/hip_runtime.h>
#include <cstddef>
#include <cstdint>

namespace {
constexpr int B_ = 8, C_ = 128, H_ = 128, W_ = 128;
constexpr int HW_ = H_ * W_;               // 16384
constexpr size_t CHW_ = (size_t)C_ * HW_;  // 2097152
constexpr int NPIX_ = B_ * HW_;            // 131072
}

typedef __attribute__((ext_vector_type(8))) short bf16x8;
typedef __attribute__((ext_vector_type(4))) float f32x4;
typedef __attribute__((ext_vector_type(16))) float f32x16;
typedef __attribute__((ext_vector_type(8))) unsigned short u16x8;
typedef __attribute__((ext_vector_type(4))) unsigned short u16x4;

__device__ inline unsigned short f2bf(float f) {
  unsigned int u = __float_as_uint(f);
  unsigned int r = u + 0x7FFFu + ((u >> 16) & 1u);
  return (unsigned short)(r >> 16);
}
__device__ inline float bf2f(unsigned short u) {
  return __uint_as_float((unsigned int)u << 16);
}

// ---- conv weight prep: symmetrize, bf16, layout [tap49][grp16][oc128][ic8]
__global__ __launch_bounds__(256) void prep_w_bf16_k(
    const float* __restrict__ Wa, const float* __restrict__ Wb,
    unsigned short* __restrict__ Ta, unsigned short* __restrict__ Tb) {
  int idx = blockIdx.x * 256 + threadIdx.x;  // 802816
  int j = idx & 7;
  int o = (idx >> 3) & 127;
  int g = (idx >> 10) & 15;
  int t = idx >> 14;
  int i = g * 8 + j;
  int ky = t / 7, kx = t - ky * 7;
  size_t oi = ((size_t)(o * 128 + i) * 7 + ky) * 7 + kx;
  size_t io = ((size_t)(i * 128 + o) * 7 + ky) * 7 + kx;
  Ta[idx] = f2bf(0.5f * (Wa[oi] + Wa[io]));
  Tb[idx] = f2bf(0.5f * (Wb[oi] + Wb[io]));
}

// ---- 1x1 weight prep: bf16 fragment layout [s12][f8][lane64][j8] -----------
__global__ __launch_bounds__(256) void prep_apack_k(
    const float* __restrict__ Wg, const float* __restrict__ Wm,
    unsigned short* __restrict__ Ag, unsigned short* __restrict__ Am) {
  int idx = blockIdx.x * 256 + threadIdx.x;  // 49152
  int j = idx & 7;
  int l = (idx >> 3) & 63;
  int f = (idx >> 9) & 7;
  int s = idx >> 12;
  int m = f * 16 + (l & 15);
  int k = s * 32 + (l >> 4) * 8 + j;
  Ag[idx] = f2bf(Wg[m * 384 + k]);
  Am[idx] = f2bf(Wm[m * 384 + k]);
}

// ---- row sums of the 1x1 weights, on bf16-rounded values (LN folding) ------
__global__ void rowsum_k(const float* __restrict__ Wg,
                         const float* __restrict__ Wm, float* __restrict__ rs) {
  int t = threadIdx.x;
  const float* src = (t < 128) ? Wg : Wm;
  int row = t & 127;
  float s = 0.f;
  for (int i = 0; i < 384; ++i) s += bf2f(f2bf(src[row * 384 + i]));
  rs[t] = s;
}

// ---- LN stats over [h_exc,h_inh,ff] + bf16 copies + partial sums over
// ---- (h_exc,h_inh) for the later g2 LN ------------------------------------
__global__ __launch_bounds__(256) void stats3_cvt_k(
    const float* __restrict__ t0, const float* __restrict__ t1,
    const float* __restrict__ t2, float* __restrict__ mu_o,
    float* __restrict__ inv_o, float* __restrict__ ps12,
    float* __restrict__ pq12, unsigned short* __restrict__ o0,
    unsigned short* __restrict__ o1, unsigned short* __restrict__ o2) {
  int q = blockIdx.x * 256 + threadIdx.x;
  int b = q >> 14, p = q & (HW_ - 1);
  size_t base = (size_t)b * CHW_ + p;
  float s = 0.f, s2 = 0.f;
  for (int c = 0; c < C_; ++c) {
    size_t a = base + (size_t)c * HW_;
    float v = t0[a]; s += v; s2 = fmaf(v, v, s2); o0[a] = f2bf(v);
  }
  for (int c = 0; c < C_; ++c) {
    size_t a = base + (size_t)c * HW_;
    float v = t1[a]; s += v; s2 = fmaf(v, v, s2); o1[a] = f2bf(v);
  }
  ps12[q] = s;
  pq12[q] = s2;
  for (int c = 0; c < C_; ++c) {
    size_t a = base + (size_t)c * HW_;
    float v = t2[a]; s += v; s2 = fmaf(v, v, s2); o2[a] = f2bf(v);
  }
  float m = s * (1.f / 384.f);
  float var = s2 * (1.f / 384.f) - m * m;
  mu_o[q] = m;
  inv_o[q] = rsqrtf(var + 1e-5f);
}

// ---- MFMA 1x1-conv gate GEMM: M=128, K=384, N=16384/batch ------------------
template <int FINAL>
__global__ __launch_bounds__(256) void gemm_mfma_k(
    const unsigned short* __restrict__ Apack, const float* __restrict__ rowsum,
    const float* __restrict__ bias, const unsigned short* __restrict__ B0,
    const unsigned short* __restrict__ B1, const unsigned short* __restrict__ B2,
    const float* __restrict__ mu, const float* __restrict__ inv,
    const float* __restrict__ mult_f32, unsigned short* __restrict__ out_cl,
    const unsigned short* __restrict__ c2raw, const float* __restrict__ muc,
    const float* __restrict__ invc, const unsigned short* __restrict__ inh_bf,
    const float* __restrict__ h_exc, const float* __restrict__ c2g,
    const float* __restrict__ c2b, const float* __restrict__ kap,
    const float* __restrict__ omg, float* __restrict__ out_f32) {
  int b = blockIdx.y;
  int tid = threadIdx.x;
  int lane = tid & 63, wid = tid >> 6;
  int l15 = lane & 15, kg = lane >> 4;
  int n0 = blockIdx.x * 128 + wid * 32;
  size_t bofs = (size_t)b * CHW_;
  f32x4 acc[8][2] = {};
  for (int s = 0; s < 12; ++s) {
    const unsigned short* src = (s < 4) ? B0 : ((s < 8) ? B1 : B2);
    const unsigned short* bp =
        src + bofs + (size_t)((s & 3) * 32 + kg * 8) * HW_ + n0 + l15;
    bf16x8 bfr[2];
#pragma unroll
    for (int nf = 0; nf < 2; ++nf) {
      const unsigned short* qp = bp + nf * 16;
      bf16x8 v;
      v[0] = (short)qp[0];
      v[1] = (short)qp[HW_];
      v[2] = (short)qp[2 * HW_];
      v[3] = (short)qp[3 * HW_];
      v[4] = (short)qp[4 * HW_];
      v[5] = (short)qp[5 * HW_];
      v[6] = (short)qp[6 * HW_];
      v[7] = (short)qp[7 * HW_];
      bfr[nf] = v;
    }
    const bf16x8* ap = (const bf16x8*)(Apack + ((size_t)(s * 8) * 64 + lane) * 8);
#pragma unroll
    for (int f = 0; f < 8; ++f) {
      bf16x8 afr = ap[f * 64];
#pragma unroll
      for (int nf = 0; nf < 2; ++nf)
        acc[f][nf] = __builtin_amdgcn_mfma_f32_16x16x32_bf16(afr, bfr[nf],
                                                             acc[f][nf], 0, 0, 0);
    }
  }
#pragma unroll
  for (int nf = 0; nf < 2; ++nf) {
    int n = n0 + nf * 16 + l15;
    int qpix = b * HW_ + n;
    float muv = mu[qpix], invv = inv[qpix];
    if (!FINAL) {
#pragma unroll
      for (int mf = 0; mf < 8; ++mf) {
        int m0 = mf * 16 + kg * 4;
        f32x4 rs4 = *(const f32x4*)(rowsum + m0);
        f32x4 bi4 = *(const f32x4*)(bias + m0);
        u16x4 st;
#pragma unroll
        for (int j = 0; j < 4; ++j) {
          float val = invv * (acc[mf][nf][j] - muv * rs4[j]) + bi4[j];
          float g = 1.f / (1.f + __expf(-val));
          float h = mult_f32[bofs + (size_t)(m0 + j) * HW_ + n];
          st[j] = f2bf(h * g);
        }
        *(u16x4*)(out_cl + (size_t)qpix * 128 + m0) = st;
      }
    } else {
      float mcv = muc[qpix], icv = invc[qpix];
#pragma unroll
      for (int mf = 0; mf < 8; ++mf) {
        int m0 = mf * 16 + kg * 4;
        f32x4 rs4 = *(const f32x4*)(rowsum + m0);
        f32x4 bi4 = *(const f32x4*)(bias + m0);
        f32x4 g4 = *(const f32x4*)(c2g + m0);
        f32x4 b4 = *(const f32x4*)(c2b + m0);
        f32x4 k4 = *(const f32x4*)(kap + m0);
        f32x4 o4 = *(const f32x4*)(omg + m0);
#pragma unroll
        for (int j = 0; j < 4; ++j) {
          size_t idx = bofs + (size_t)(m0 + j) * HW_ + n;
          float val = invv * (acc[mf][nf][j] - muv * rs4[j]) + bi4[j];
          float g2 = 1.f / (1.f + __expf(-val));
          float c2 = (bf2f(c2raw[idx]) - mcv) * icv * g4[j] + b4[j];
          float iv = bf2f(inh_bf[idx]);
          float ht =
              fmaxf(k4[j] * (iv + c2) + fmaxf(o4[j], 0.f) * (iv * c2), 0.f);
          out_f32[idx] = (1.f - g2) * h_exc[idx] + g2 * ht;
        }
      }
    }
  }
}

// ---- 7x7 SAME conv via 32x32x16 MFMA; weights direct-from-global; ----------
// ---- ring-buffered input rows; fused per-pixel LN stats --------------------
// Block: 256 thr = 4 waves, tile 128oc x (2 rows x 128 px).
// Wave (wm, wn): 64 oc x 1 row (128 px). in_s ring: 2 rows x 32ic staged.
__global__ __launch_bounds__(256, 2) void conv7_mfma_k(
    const unsigned short* __restrict__ in_cl,
    const unsigned short* __restrict__ Wp, unsigned short* __restrict__ out,
    float* __restrict__ mu_o, float* __restrict__ inv_o) {
  __shared__ short in_s[2][4][136][8];  // [slot][g][xi][ic8] 17408 B
  __shared__ float red_s[2][2][128];
  __shared__ float red_q[2][2][128];
  int b = blockIdx.x >> 6;
  int y0 = (blockIdx.x & 63) * 2;
  int tid = threadIdx.x;
  int lane = tid & 63, wid = tid >> 6;
  int wm = wid >> 1, wn = wid & 1;
  int l31 = lane & 31, lh = lane >> 5;
  const unsigned short* inb = in_cl + (size_t)b * CHW_;
  // staging geometry (fixed per thread): 544 lane-chunks per row
  int pg[3], pxi[3];
#pragma unroll
  for (int it = 0; it < 3; ++it) {
    int u = tid + it * 256;
    pg[it] = u / 136;
    pxi[it] = u - pg[it] * 136;
  }
  f32x16 acc[2][4] = {};  // [oct][nf]
  for (int c4 = 0; c4 < 4; ++c4) {
    __syncthreads();  // protect previous c4's reads
    // initial stage: rows y0-3, y0-2
#pragma unroll
    for (int r = 0; r < 2; ++r) {
      int y = y0 - 3 + r;
      int slot = y & 1;
#pragma unroll
      for (int it = 0; it < 3; ++it) {
        int u = tid + it * 256;
        if (u < 544) {
          int x = pxi[it] - 3;
          u16x8 v = {};
          if (x >= 0 && x < 128 && y >= 0)
            v = *(const u16x8*)(inb +
                                ((size_t)(y * 128 + x) * 128 + c4 * 32 + pg[it] * 8));
          *(u16x8*)(&in_s[slot][pg[it]][pxi[it]][0]) = v;
        }
      }
    }
    __syncthreads();
    for (int ky = 0; ky < 7; ++ky) {
      // prefetch (into regs) the row needed at ky+1
      int nrow = y0 + ky - 1;
      u16x8 pf[3];
#pragma unroll
      for (int it = 0; it < 3; ++it) {
        int u = tid + it * 256;
        pf[it] = u16x8{};
        if (ky < 6 && u < 544) {
          int x = pxi[it] - 3;
          if (x >= 0 && x < 128 && nrow >= 0 && nrow < 128)
            pf[it] = *(const u16x8*)(inb + ((size_t)(nrow * 128 + x) * 128 +
                                            c4 * 32 + pg[it] * 8));
        }
      }
      // compute ky
      int srow = (y0 + wn + ky - 3) & 1;
      const short* irow = &in_s[srow][0][0][0] + (lh * 136 + l31) * 8;
      const unsigned short* wb =
          Wp + ((size_t)(ky * 7 * 16 + c4 * 4 + lh) * 128 + wm * 64 + l31) * 8;
#pragma unroll
      for (int kx = 0; kx < 7; ++kx) {
        bf16x8 afr[2][2], bfr[2][4];
#pragma unroll
        for (int ks = 0; ks < 2; ++ks) {
#pragma unroll
          for (int oct = 0; oct < 2; ++oct)
            afr[ks][oct] =
                *(const bf16x8*)(wb + kx * 16384 + ks * 2048 + oct * 256);
#pragma unroll
          for (int nf = 0; nf < 4; ++nf)
            bfr[ks][nf] = *(const bf16x8*)(irow + (ks * 272 + nf * 32 + kx) * 8);
        }
#pragma unroll
        for (int ks = 0; ks < 2; ++ks)
#pragma unroll
          for (int oct = 0; oct < 2; ++oct)
#pragma unroll
            for (int nf = 0; nf < 4; ++nf)
              acc[oct][nf] = __builtin_amdgcn_mfma_f32_32x32x16_bf16(
                  afr[ks][oct], bfr[ks][nf], acc[oct][nf], 0, 0, 0);
      }
      // commit prefetched row to its ring slot
      if (ky < 6) {
        __syncthreads();
        int slot = nrow & 1;
#pragma unroll
        for (int it = 0; it < 3; ++it) {
          int u = tid + it * 256;
          if (u < 544) *(u16x8*)(&in_s[slot][pg[it]][pxi[it]][0]) = pf[it];
        }
        __syncthreads();
      }
    }
  }
  // epilogue: store bf16 NCHW + fused per-pixel LN stats
  int y = y0 + wn;
  size_t ob = (size_t)b * CHW_ + (size_t)y * 128;
#pragma unroll
  for (int nf = 0; nf < 4; ++nf) {
    int x = nf * 32 + l31;
    float s = 0.f, qq = 0.f;
#pragma unroll
    for (int oct = 0; oct < 2; ++oct) {
#pragma unroll
      for (int j = 0; j < 16; ++j) {
        int oc = wm * 64 + oct * 32 + lh * 4 + (j & 3) + 8 * (j >> 2);
        unsigned short bv = f2bf(acc[oct][nf][j]);
        float vr = bf2f(bv);
        s += vr;
        qq = fmaf(vr, vr, qq);
        out[ob + (size_t)oc * HW_ + x] = bv;
      }
    }
    s += __shfl_xor(s, 32);
    qq += __shfl_xor(qq, 32);
    if (lh == 0) {
      red_s[wm][wn][x] = s;
      red_q[wm][wn][x] = qq;
    }
  }
  __syncthreads();
  {
    int wn2 = tid >> 7, x2 = tid & 127;
    float s = red_s[0][wn2][x2] + red_s[1][wn2][x2];
    float qq = red_q[0][wn2][x2] + red_q[1][wn2][x2];
    float m = s * (1.f / 128.f);
    float var = qq * (1.f / 128.f) - m * m;
    int q = b * HW_ + (y0 + wn2) * 128 + x2;
    mu_o[q] = m;
    inv_o[q] = rsqrtf(var + 1e-5f);
  }
}

// ---- inhibited = relu(ff - relu((sig(alpha)*h_inh+mu)*LN(c1))) --------------
// + fused g2 LN stats (own sums + precomputed h_exc/h_inh partials)
__global__ __launch_bounds__(256) void inhibit_k(
    const unsigned short* __restrict__ c1_raw_bf, const float* __restrict__ ff,
    const unsigned short* __restrict__ hinh_bf, const float* __restrict__ mu_s,
    const float* __restrict__ inv_s, const float* __restrict__ ps12,
    const float* __restrict__ pq12, const float* __restrict__ alpha,
    const float* __restrict__ mu_p, const float* __restrict__ gamma,
    const float* __restrict__ beta, unsigned short* __restrict__ out_nchw,
    unsigned short* __restrict__ out_cl, float* __restrict__ mu2_o,
    float* __restrict__ inv2_o) {
  __shared__ unsigned short tile[32 * 136];
  __shared__ float s8[8][32];
  __shared__ float q8[8][32];
  int blk = blockIdx.x;
  int b = blk >> 9;
  int p0 = (blk & 511) * 32;
  int t = threadIdx.x;
  int px = t & 31, cq = t >> 5;
  int q = b * HW_ + p0 + px;
  float muv = mu_s[q], invv = inv_s[q];
  size_t pixbase = (size_t)b * CHW_ + p0 + px;
  float sp = 0.f, qp = 0.f;
  for (int ci = 0; ci < 16; ++ci) {
    int c = cq * 16 + ci;
    size_t idx = pixbase + (size_t)c * HW_;
    float c1 = (bf2f(c1_raw_bf[idx]) - muv) * invv * gamma[c] + beta[c];
    float a = 1.f / (1.f + __expf(-alpha[c]));
    float r = fmaxf((a * bf2f(hinh_bf[idx]) + mu_p[c]) * c1, 0.f);
    float v = fmaxf(ff[idx] - r, 0.f);
    unsigned short bv = f2bf(v);
    float vr = bf2f(bv);
    sp += vr;
    qp = fmaf(vr, vr, qp);
    out_nchw[idx] = bv;
    tile[px * 136 + c] = bv;
  }
  s8[cq][px] = sp;
  q8[cq][px] = qp;
  __syncthreads();
#pragma unroll
  for (int pass = 0; pass < 2; ++pass) {
    int u = pass * 256 + t;
    int ppx = u >> 4, cg = u & 15;
    u16x8 v = *(const u16x8*)(tile + ppx * 136 + cg * 8);
    *(u16x8*)(out_cl + (size_t)(b * HW_ + p0 + ppx) * 128 + cg * 8) = v;
  }
  if (t < 32) {
    float s = 0.f, qsum = 0.f;
#pragma unroll
    for (int k = 0; k < 8; ++k) {
      s += s8[k][t];
      qsum += q8[k][t];
    }
    int qn = b * HW_ + p0 + t;
    s += ps12[qn];
    qsum += pq12[qn];
    float m = s * (1.f / 384.f);
    float var = qsum * (1.f / 384.f) - m * m;
    mu2_o[qn] = m;
    inv2_o[qn] = rsqrtf(var + 1e-5f);
  }
}

extern "C" void kernel_launch(void* const* d_in, const int* in_sizes, int n_in,
                              void* d_out, int out_size, void* d_ws,
                              size_t ws_size, hipStream_t stream) {
  const float* ff     = (const float*)d_in[0];
  const float* h_exc  = (const float*)d_in[1];
  const float* h_inh  = (const float*)d_in[2];
  const float* W_gain = (const float*)d_in[3];
  const float* b_gain = (const float*)d_in[4];
  const float* W_mix  = (const float*)d_in[5];
  const float* b_mix  = (const float*)d_in[6];
  const float* W_inh  = (const float*)d_in[7];
  const float* W_exc  = (const float*)d_in[8];
  const float* alpha  = (const float*)d_in[9];
  const float* mu_p   = (const float*)d_in[10];
  const float* kappa  = (const float*)d_in[11];
  const float* omega  = (const float*)d_in[12];
  const float* c1_g   = (const float*)d_in[13];
  const float* c1_b   = (const float*)d_in[14];
  const float* c2_g   = (const float*)d_in[15];
  const float* c2_b   = (const float*)d_in[16];

  float* w = (float*)d_ws;
  unsigned short* Wp_inh = (unsigned short*)w;  w += 401408;
  unsigned short* Wp_exc = (unsigned short*)w;  w += 401408;
  unsigned short* Ag     = (unsigned short*)w;  w += 24576;
  unsigned short* Am     = (unsigned short*)w;  w += 24576;
  float* rs     = w;  w += 256;
  float* mu1    = w;  w += NPIX_;
  float* inv1   = w;  w += NPIX_;
  float* mu_c1  = w;  w += NPIX_;
  float* inv_c1 = w;  w += NPIX_;
  float* mu2    = w;  w += NPIX_;
  float* inv2   = w;  w += NPIX_;
  float* mu_c2  = w;  w += NPIX_;
  float* inv_c2 = w;  w += NPIX_;
  float* ps12   = w;  w += NPIX_;
  float* pq12   = w;  w += NPIX_;
  unsigned short* exc_bf   = (unsigned short*)w;  w += 8388608;
  unsigned short* hinh_bf  = (unsigned short*)w;  w += 8388608;
  unsigned short* ffinh_bf = (unsigned short*)w;  w += 8388608;  // ff, then inhibited
  unsigned short* conv_bf  = (unsigned short*)w;  w += 8388608;  // c1_raw, then c2_raw

  unsigned short* gated_cl = (unsigned short*)d_out;
  unsigned short* inh_cl   = (unsigned short*)d_out + (size_t)16777216;

  prep_w_bf16_k<<<3136, 256, 0, stream>>>(W_inh, W_exc, Wp_inh, Wp_exc);
  prep_apack_k<<<192, 256, 0, stream>>>(W_gain, W_mix, Ag, Am);
  rowsum_k<<<1, 256, 0, stream>>>(W_gain, W_mix, rs);

  // g1 LN stats + bf16 copies + (h_exc,h_inh) partial sums for g2
  stats3_cvt_k<<<512, 256, 0, stream>>>(h_exc, h_inh, ff, mu1, inv1, ps12,
                                        pq12, exc_bf, hinh_bf, ffinh_bf);
  // gated = h_exc * g1  (bf16 channels-last into d_out lo)
  {
    dim3 g(128, 8);
    gemm_mfma_k<0><<<g, 256, 0, stream>>>(
        Ag, rs, b_gain, exc_bf, hinh_bf, ffinh_bf, mu1, inv1, h_exc, gated_cl,
        nullptr, nullptr, nullptr, nullptr, nullptr, nullptr, nullptr, nullptr,
        nullptr, nullptr);
  }
  // c1 = sym_conv(gated) + fused LN stats
  conv7_mfma_k<<<512, 256, 0, stream>>>(gated_cl, Wp_inh, conv_bf, mu_c1,
                                        inv_c1);
  // inhibited + fused g2 LN stats
  inhibit_k<<<4096, 256, 0, stream>>>(conv_bf, ff, hinh_bf, mu_c1, inv_c1,
                                      ps12, pq12, alpha, mu_p, c1_g, c1_b,
                                      ffinh_bf, inh_cl, mu2, inv2);
  // c2 = sym_conv(inhibited) + fused LN stats
  conv7_mfma_k<<<512, 256, 0, stream>>>(inh_cl, Wp_exc, conv_bf, mu_c2,
                                        inv_c2);
  // g2 gemm + fused final mix -> d_out f32 NCHW
  {
    dim3 g(128, 8);
    gemm_mfma_k<1><<<g, 256, 0, stream>>>(
        Am, rs + 128, b_mix, ffinh_bf, exc_bf, hinh_bf, mu2, inv2, nullptr,
        nullptr, conv_bf, mu_c2, inv_c2, ffinh_bf, h_exc, c2_g, c2_b, kappa,
        omega, (float*)d_out);
  }
}